// Round 7
// baseline (277.762 us; speedup 1.0000x reference)
//
#include <hip/hip_runtime.h>
#include <stdint.h>

// Problem constants (fixed by reference setup_inputs)
#define NTOK   8192
#define NEXP   64
#define HID    4096
#define TOPK   8
#define OUTROW 65536   // NTOK * TOPK
#define CHUNK  256     // tokens per chunk
#define NCHUNK 32      // NTOK / CHUNK
#define NPART  2048    // NEXP * NCHUNK, expert-major chunk-minor

typedef float f32x4 __attribute__((ext_vector_type(4)));
typedef unsigned long long u64;

// ---------------------------------------------------------------------------
// K1: per-token expert bitmasks + per-(expert,chunk) counts.
// 2048 blocks x 256 threads, block b = (e<<5)|c. Mask build: wave reads one
// token's 64-expert row COALESCED (lane = expert, 256B per load) and ballots
// it into a 64-bit mask. All 64 blocks of a chunk rebuild the same masks from
// the L2-hot map slice (cheap); only the e==0 block writes masks to global.
__global__ void mask_count_kernel(const int* __restrict__ map,
                                  u64* __restrict__ masks,
                                  int* __restrict__ pcnt) {
    int b = blockIdx.x;
    int e = b >> 5, c = b & (NCHUNK - 1);
    int tid = threadIdx.x;
    int w = tid >> 6, lane = tid & 63;

    __shared__ u64 sm[CHUNK];
    int t0 = c * CHUNK + w * 64;
#pragma unroll 8
    for (int i = 0; i < 64; ++i) {
        int v = map[(size_t)(t0 + i) * NEXP + lane];   // coalesced: lane = expert
        u64 bal = __ballot(v != 0);
        if (lane == 0) sm[w * 64 + i] = bal;
    }
    __syncthreads();
    if (e == 0) masks[c * CHUNK + tid] = sm[tid];      // global token id = c*256+tid

    // count bit e over this chunk's 256 masks
    __shared__ int red[256];
    red[tid] = (int)((sm[tid] >> e) & 1ull);
    __syncthreads();
    for (int off = 128; off > 0; off >>= 1) {
        if (tid < off) red[tid] += red[tid + off];
        __syncthreads();
    }
    if (tid == 0) pcnt[b] = red[0];
}

// ---------------------------------------------------------------------------
// K2: position assignment, atomic-free. Block b = (e<<5)|c, 256 threads,
// thread tid <-> token t = c*256+tid. Exclusive base from pcnt prefix
// (L2-resident); ballot rank preserves token order; inverse-map slot is the
// deterministic rank of e within the token's mask.
__global__ void assign_kernel(const u64* __restrict__ masks,
                              const float* __restrict__ probs,
                              const int* __restrict__ pcnt,
                              int* __restrict__ tok_pos,
                              float* __restrict__ probs_out,
                              float* __restrict__ idx_out) {
    int b = blockIdx.x;
    int e = b >> 5, c = b & (NCHUNK - 1);
    int tid = threadIdx.x;
    int w = tid >> 6, lane = tid & 63;

    __shared__ int red[256];
    __shared__ int wcnt[4];

    // exclusive base = sum(pcnt[0..b-1])
    int acc = 0;
    for (int i = tid; i < b; i += 256) acc += pcnt[i];
    red[tid] = acc;
    __syncthreads();
    for (int off = 128; off > 0; off >>= 1) {
        if (tid < off) red[tid] += red[tid + off];
        __syncthreads();
    }
    int base = red[0];

    int t = c * CHUNK + tid;
    u64 mk = masks[t];                                  // coalesced 8B
    bool m = (mk >> e) & 1ull;
    u64 bal = __ballot(m);
    int rank = __popcll(bal & ((1ull << lane) - 1ull));
    if (lane == 0) wcnt[w] = __popcll(bal);
    __syncthreads();
    int wbase = 0;
#pragma unroll
    for (int i = 0; i < 4; ++i) wbase += (i < w) ? wcnt[i] : 0;

    if (m) {
        int pos = base + wbase + rank;
        idx_out[pos] = (float)t;                        // exact for t < 2^24
        probs_out[pos] = probs[(size_t)t * NEXP + e];
        int slot = __popcll(mk & ((1ull << e) - 1ull)); // rank of e in mask
        if (slot < TOPK) tok_pos[t * TOPK + slot] = pos;
    }
}

// ---------------------------------------------------------------------------
// K3: token-major gather. One block per token: read the 16 KB row once into
// registers, store to all TOPK destinations (each contiguous 16 KB). Plain
// loads/stores (same path as the 6.5 TB/s fill kernels); tok_pos reads are
// block-uniform -> scalarized. No LDS, no barriers.
__global__ void gather_kernel(const float* __restrict__ tokens,
                              const int* __restrict__ tok_pos,
                              float* __restrict__ out_rows) {
    int t = blockIdx.x;
    int tid = threadIdx.x;
    const f32x4* sp = (const f32x4*)(tokens + (size_t)t * HID);
    f32x4 v0 = sp[tid];
    f32x4 v1 = sp[tid + 256];
    f32x4 v2 = sp[tid + 512];
    f32x4 v3 = sp[tid + 768];
#pragma unroll
    for (int j = 0; j < TOPK; ++j) {
        unsigned p = (unsigned)tok_pos[t * TOPK + j];   // uniform per block
        if (p >= OUTROW) continue;                      // defensive: never fault
        f32x4* dp = (f32x4*)(out_rows + (size_t)p * HID);
        dp[tid]       = v0;
        dp[tid + 256] = v1;
        dp[tid + 512] = v2;
        dp[tid + 768] = v3;
    }
}

// ---------------------------------------------------------------------------
extern "C" void kernel_launch(void* const* d_in, const int* in_sizes, int n_in,
                              void* d_out, int out_size, void* d_ws, size_t ws_size,
                              hipStream_t stream) {
    const float* tokens = (const float*)d_in[0];
    const float* probs  = (const float*)d_in[1];
    const int*   map    = (const int*)d_in[2];

    float* out_rows  = (float*)d_out;                    // [OUTROW, HID]
    float* out_probs = out_rows + (size_t)OUTROW * HID;  // [OUTROW]
    float* out_idx   = out_probs + OUTROW;               // [OUTROW] float-coded ids

    // workspace: masks 64KB (u64, aligned first) + pcnt 8KB + tok_pos 256KB
    u64* masks   = (u64*)d_ws;
    int* pcnt    = (int*)(masks + NTOK);
    int* tok_pos = pcnt + NPART;

    mask_count_kernel<<<NPART, 256, 0, stream>>>(map, masks, pcnt);
    assign_kernel<<<NPART, 256, 0, stream>>>(masks, probs, pcnt, tok_pos,
                                             out_probs, out_idx);
    gather_kernel<<<NTOK, 256, 0, stream>>>(tokens, tok_pos, out_rows);
}

// Round 8
// 271.351 us; speedup vs baseline: 1.0236x; 1.0236x over previous
//
#include <hip/hip_runtime.h>
#include <stdint.h>

// Problem constants (fixed by reference setup_inputs)
#define NTOK   8192
#define NEXP   64
#define HID    4096
#define TOPK   8
#define OUTROW 65536   // NTOK * TOPK
#define CHUNK  256     // tokens per chunk
#define NCHUNK 32      // NTOK / CHUNK
#define NPART  2048    // NEXP * NCHUNK, expert-major chunk-minor

typedef float f32x4 __attribute__((ext_vector_type(4)));
typedef unsigned long long u64;

// ---------------------------------------------------------------------------
// K1: per-token expert bitmasks + all per-(expert,chunk) counts.
// 32 blocks x 256 threads (one block per token chunk) — map is read EXACTLY
// once (2 MB, coalesced: lane = expert). Counts via LDS histogram: every token
// has exactly TOPK=8 set bits -> 8 LDS atomics per thread.
__global__ void mask_count_kernel(const int* __restrict__ map,
                                  u64* __restrict__ masks,
                                  int* __restrict__ pcnt) {
    int c = blockIdx.x;
    int tid = threadIdx.x;
    int w = tid >> 6, lane = tid & 63;

    __shared__ u64 sm[CHUNK];
    __shared__ int hcnt[NEXP];
    if (tid < NEXP) hcnt[tid] = 0;

    int t0 = c * CHUNK + w * 64;
#pragma unroll 8
    for (int i = 0; i < 64; ++i) {
        int v = map[(size_t)(t0 + i) * NEXP + lane];   // coalesced: lane = expert
        u64 bal = __ballot(v != 0);
        if (lane == 0) sm[w * 64 + i] = bal;
    }
    __syncthreads();

    u64 mk = sm[tid];
    masks[c * CHUNK + tid] = mk;                       // global token id = c*256+tid
    while (mk) {
        int e = __ffsll((long long)mk) - 1;
        atomicAdd(&hcnt[e], 1);
        mk &= mk - 1;
    }
    __syncthreads();
    if (tid < NEXP) pcnt[tid * NCHUNK + c] = hcnt[tid]; // [e][c] layout
}

// ---------------------------------------------------------------------------
// K2: position assignment, atomic-free. Block b = (e<<5)|c, 256 threads,
// thread tid <-> token t = c*256+tid. Exclusive base from pcnt prefix
// (L2-resident); ballot rank preserves token order; inverse-map slot is the
// deterministic rank of e within the token's mask.
__global__ void assign_kernel(const u64* __restrict__ masks,
                              const float* __restrict__ probs,
                              const int* __restrict__ pcnt,
                              int* __restrict__ tok_pos,
                              float* __restrict__ probs_out,
                              float* __restrict__ idx_out) {
    int b = blockIdx.x;
    int e = b >> 5, c = b & (NCHUNK - 1);
    int tid = threadIdx.x;
    int w = tid >> 6, lane = tid & 63;

    __shared__ int red[256];
    __shared__ int wcnt[4];

    // exclusive base = sum(pcnt[0..b-1])
    int acc = 0;
    for (int i = tid; i < b; i += 256) acc += pcnt[i];
    red[tid] = acc;
    __syncthreads();
    for (int off = 128; off > 0; off >>= 1) {
        if (tid < off) red[tid] += red[tid + off];
        __syncthreads();
    }
    int base = red[0];

    int t = c * CHUNK + tid;
    u64 mk = masks[t];                                  // coalesced 8B
    bool m = (mk >> e) & 1ull;
    u64 bal = __ballot(m);
    int rank = __popcll(bal & ((1ull << lane) - 1ull));
    if (lane == 0) wcnt[w] = __popcll(bal);
    __syncthreads();
    int wbase = 0;
#pragma unroll
    for (int i = 0; i < 4; ++i) wbase += (i < w) ? wcnt[i] : 0;

    if (m) {
        int pos = base + wbase + rank;
        idx_out[pos] = (float)t;                        // exact for t < 2^24
        probs_out[pos] = probs[(size_t)t * NEXP + e];
        int slot = __popcll(mk & ((1ull << e) - 1ull)); // rank of e in mask
        if (slot < TOPK) tok_pos[t * TOPK + slot] = pos;
    }
}

// ---------------------------------------------------------------------------
// K3: token-major gather (round-6 nt path). One block per token: nontemporal-
// read the 16 KB row once into registers (single-use data, bypass caches),
// nontemporal-store to all TOPK destinations (each contiguous 16 KB; the
// 1.07 GB stream must not thrash L2/LLC against concurrent reads).
// tok_pos reads are block-uniform -> scalarized; no LDS, no barriers.
__global__ void gather_kernel(const float* __restrict__ tokens,
                              const int* __restrict__ tok_pos,
                              float* __restrict__ out_rows) {
    int t = blockIdx.x;
    int tid = threadIdx.x;
    const f32x4* sp = (const f32x4*)(tokens + (size_t)t * HID);
    f32x4 v0 = __builtin_nontemporal_load(sp + tid);
    f32x4 v1 = __builtin_nontemporal_load(sp + tid + 256);
    f32x4 v2 = __builtin_nontemporal_load(sp + tid + 512);
    f32x4 v3 = __builtin_nontemporal_load(sp + tid + 768);
#pragma unroll
    for (int j = 0; j < TOPK; ++j) {
        unsigned p = (unsigned)tok_pos[t * TOPK + j];   // uniform per block
        if (p >= OUTROW) continue;                      // defensive: never fault
        f32x4* dp = (f32x4*)(out_rows + (size_t)p * HID);
        __builtin_nontemporal_store(v0, dp + tid);
        __builtin_nontemporal_store(v1, dp + tid + 256);
        __builtin_nontemporal_store(v2, dp + tid + 512);
        __builtin_nontemporal_store(v3, dp + tid + 768);
    }
}

// ---------------------------------------------------------------------------
extern "C" void kernel_launch(void* const* d_in, const int* in_sizes, int n_in,
                              void* d_out, int out_size, void* d_ws, size_t ws_size,
                              hipStream_t stream) {
    const float* tokens = (const float*)d_in[0];
    const float* probs  = (const float*)d_in[1];
    const int*   map    = (const int*)d_in[2];

    float* out_rows  = (float*)d_out;                    // [OUTROW, HID]
    float* out_probs = out_rows + (size_t)OUTROW * HID;  // [OUTROW]
    float* out_idx   = out_probs + OUTROW;               // [OUTROW] float-coded ids

    // workspace: masks 64KB (u64, aligned first) + pcnt 8KB + tok_pos 256KB
    u64* masks   = (u64*)d_ws;
    int* pcnt    = (int*)(masks + NTOK);
    int* tok_pos = pcnt + NPART;

    mask_count_kernel<<<NCHUNK, CHUNK, 0, stream>>>(map, masks, pcnt);
    assign_kernel<<<NPART, CHUNK, 0, stream>>>(masks, probs, pcnt, tok_pos,
                                               out_probs, out_idx);
    gather_kernel<<<NTOK, CHUNK, 0, stream>>>(tokens, tok_pos, out_rows);
}

// Round 9
// 266.692 us; speedup vs baseline: 1.0415x; 1.0175x over previous
//
#include <hip/hip_runtime.h>
#include <stdint.h>

// Problem constants (fixed by reference setup_inputs)
#define NTOK   8192
#define NEXP   64
#define HID    4096
#define TOPK   8
#define OUTROW 65536   // NTOK * TOPK
#define CHUNK  256     // tokens per chunk
#define NCHUNK 32      // NTOK / CHUNK
#define NPART  2048    // NEXP * NCHUNK, expert-major chunk-minor

typedef float f32x4 __attribute__((ext_vector_type(4)));
typedef unsigned long long u64;

// ---------------------------------------------------------------------------
// K1: per-token expert bitmasks + per-(expert,chunk) counts.
// 32 blocks x 256 threads (one block per token chunk) — map read exactly once
// (2 MB, coalesced: lane = expert).
__global__ void mask_count_kernel(const int* __restrict__ map,
                                  u64* __restrict__ masks,
                                  int* __restrict__ pcnt) {
    int c = blockIdx.x;
    int tid = threadIdx.x;
    int w = tid >> 6, lane = tid & 63;

    __shared__ u64 sm[CHUNK];
    __shared__ int hcnt[NEXP];
    if (tid < NEXP) hcnt[tid] = 0;

    int t0 = c * CHUNK + w * 64;
#pragma unroll 8
    for (int i = 0; i < 64; ++i) {
        int v = map[(size_t)(t0 + i) * NEXP + lane];   // coalesced: lane = expert
        u64 bal = __ballot(v != 0);
        if (lane == 0) sm[w * 64 + i] = bal;
    }
    __syncthreads();

    u64 mk = sm[tid];
    masks[c * CHUNK + tid] = mk;                       // global token id = c*256+tid
    while (mk) {
        int e = __ffsll((long long)mk) - 1;
        atomicAdd(&hcnt[e], 1);
        mk &= mk - 1;
    }
    __syncthreads();
    if (tid < NEXP) pcnt[tid * NCHUNK + c] = hcnt[tid]; // flat [e][c] layout
}

// ---------------------------------------------------------------------------
// K2: exclusive prefix over the 2048 flat (expert-major, chunk-minor) counts.
// One block, 256 threads, 8 values/thread.
__global__ void scan_kernel(const int* __restrict__ pcnt, int* __restrict__ poffs) {
    __shared__ int s[256];
    int tid = threadIdx.x;
    int v[8];
    int sum = 0;
#pragma unroll
    for (int i = 0; i < 8; ++i) { v[i] = pcnt[tid * 8 + i]; sum += v[i]; }
    s[tid] = sum;
    __syncthreads();
    for (int off = 1; off < 256; off <<= 1) {
        int x = (tid >= off) ? s[tid - off] : 0;
        __syncthreads();
        s[tid] += x;
        __syncthreads();
    }
    int base = (tid == 0) ? 0 : s[tid - 1];  // exclusive
#pragma unroll
    for (int i = 0; i < 8; ++i) { poffs[tid * 8 + i] = base; base += v[i]; }
}

// ---------------------------------------------------------------------------
// K3 (mega): one block per token. Computes the token's 8 output positions
// in-kernel (poffs lookup + packed-u64 rank reduction), writes probs/idx for
// its 8 entries, then streams the 16 KB row (nt read once into registers,
// nt store to 8 contiguous 16 KB destinations).
// rank packing: thread i < tin contributes bit (mask_i >> e_j) in 8-bit field
// j; fields <= 255 since tin <= 255 -> no overflow. One tree reduction gives
// all 8 intra-chunk ranks.
__global__ void mega_kernel(const u64* __restrict__ masks,
                            const float* __restrict__ probs,
                            const int* __restrict__ poffs,
                            const float* __restrict__ tokens,
                            float* __restrict__ out_rows,
                            float* __restrict__ out_probs,
                            float* __restrict__ out_idx) {
    int t = blockIdx.x;
    int c = t >> 8, tin = t & 255;
    int tid = threadIdx.x;

    // issue the row read early; consumed only at the stores
    const f32x4* sp = (const f32x4*)(tokens + (size_t)t * HID);
    f32x4 v0 = __builtin_nontemporal_load(sp + tid);
    f32x4 v1 = __builtin_nontemporal_load(sp + tid + 256);
    f32x4 v2 = __builtin_nontemporal_load(sp + tid + 512);
    f32x4 v3 = __builtin_nontemporal_load(sp + tid + 768);

    __shared__ u64 red[256];
    __shared__ int s_pos[TOPK];

    // this token's expert list (exactly TOPK set bits)
    u64 mk = masks[t];
    int e[TOPK];
    u64 tmp = mk;
#pragma unroll
    for (int j = 0; j < TOPK; ++j) {
        e[j] = tmp ? (__ffsll((long long)tmp) - 1) : 0;  // defensive
        tmp &= tmp - 1;
    }

    // packed contributions of earlier tokens in the chunk
    u64 contrib = 0;
    if (tid < tin) {
        u64 mi = masks[c * CHUNK + tid];
#pragma unroll
        for (int j = 0; j < TOPK; ++j)
            contrib |= ((mi >> e[j]) & 1ull) << (8 * j);
    }
    red[tid] = contrib;
    __syncthreads();
    for (int off = 128; off > 0; off >>= 1) {
        if (tid < off) red[tid] += red[tid + off];
        __syncthreads();
    }
    u64 ranks = red[0];

    if (tid < TOPK) {
        int ej = e[tid];
        int pos = poffs[ej * NCHUNK + c] + (int)((ranks >> (8 * tid)) & 0xff);
        if ((unsigned)pos >= OUTROW) pos = 0;            // defensive: never fault
        s_pos[tid] = pos;
        out_idx[pos] = (float)t;                         // exact for t < 2^24
        out_probs[pos] = probs[(size_t)t * NEXP + ej];
    }
    __syncthreads();

#pragma unroll
    for (int j = 0; j < TOPK; ++j) {
        int p = s_pos[j];
        f32x4* dp = (f32x4*)(out_rows + (size_t)p * HID);
        __builtin_nontemporal_store(v0, dp + tid);
        __builtin_nontemporal_store(v1, dp + tid + 256);
        __builtin_nontemporal_store(v2, dp + tid + 512);
        __builtin_nontemporal_store(v3, dp + tid + 768);
    }
}

// ---------------------------------------------------------------------------
extern "C" void kernel_launch(void* const* d_in, const int* in_sizes, int n_in,
                              void* d_out, int out_size, void* d_ws, size_t ws_size,
                              hipStream_t stream) {
    const float* tokens = (const float*)d_in[0];
    const float* probs  = (const float*)d_in[1];
    const int*   map    = (const int*)d_in[2];

    float* out_rows  = (float*)d_out;                    // [OUTROW, HID]
    float* out_probs = out_rows + (size_t)OUTROW * HID;  // [OUTROW]
    float* out_idx   = out_probs + OUTROW;               // [OUTROW] float-coded ids

    // workspace: masks 64KB (u64, aligned first) + pcnt 8KB + poffs 8KB
    u64* masks = (u64*)d_ws;
    int* pcnt  = (int*)(masks + NTOK);
    int* poffs = pcnt + NPART;

    mask_count_kernel<<<NCHUNK, CHUNK, 0, stream>>>(map, masks, pcnt);
    scan_kernel<<<1, CHUNK, 0, stream>>>(pcnt, poffs);
    mega_kernel<<<NTOK, CHUNK, 0, stream>>>(masks, probs, poffs, tokens,
                                            out_rows, out_probs, out_idx);
}